// Round 2
// baseline (106.601 us; speedup 1.0000x reference)
//
#include <hip/hip_runtime.h>
#include <math.h>

#define OBS 8
#define ACT 4
#define DIN 12
#define NTRAIN 128
#define BATCH 8
#define NPAIR 36               // triangle a<=c
#define NBLK (BATCH*NPAIR)     // 288 blocks (gp tasks merged into diag blocks)
#define THREADS 512
#define HSTRIDE 16             // floats per h row (64B; 2-way write alias = free)

// ws layout (floats)
#define WS_PM  0               // 64   pred_mean[b][e]
#define WS_CC  64              // 768  cross_cov[b][d][e]
#define WS_MN  832             // 512  main[b][a][c]
#define WS_TR  1344            // 64   trace[b][e]
#define WS_CNT 1536            // 1    completion counter (memset to 0 per launch)

// ---------------------------------------------------------------------------
// Single kernel: 288 blocks x 512 threads (8 waves), plain launch.
// Every block is a pair task (a<=c). Diag blocks (a==c) additionally run the
// gp predictive task for e=a: its 12x12 B-inverse is computed by lanes 16..27
// of wave 0 in the SAME shuffle-GJ pass that lanes 0..11 use for M, and its
// per-point work runs on waves 2..3 (idle during stage 2a before this merge).
// Epilogue: last-block-done pattern — device-scope atomic counter in ws; the
// block observing old==NBLK-1 runs the former k_final for all 8 batches
// (wave w <-> batch w). No co-residency requirement, no spin, capturable.
// __launch_bounds__(512,4): cap VGPR<=128 so 2 blocks/CU co-reside (288>256).
// ---------------------------------------------------------------------------
__global__ void __launch_bounds__(THREADS, 4) k_all(
    const float* __restrict__ m_x, const float* __restrict__ s_x,
    const float* __restrict__ m_u, const float* __restrict__ s_u,
    const float* __restrict__ c_xu, const float* __restrict__ X,
    const float* __restrict__ ls, const float* __restrict__ vars,
    const float* __restrict__ noises, const float* __restrict__ beta,
    const float* __restrict__ invK, float* __restrict__ ws,
    float* __restrict__ out)
{
    int blk = blockIdx.x, tid = threadIdx.x;
    int lane = tid & 63, w = tid >> 6;
    int b = blk / NPAIR;
    int rem = blk % NPAIR;
    int a = 0;
    while (rem >= OBS - a) { rem -= OBS - a; a++; }
    int c = a + rem;
    bool diag = (a == c);

    __shared__ float jvs[144];          // joint_var
    __shared__ float Wl[144];           // pair M-inverse
    __shared__ float Wg[144];           // gp B-inverse (diag blocks)
    __shared__ float mu[DIN];
    __shared__ float sc_wsum[DIN], sc_iA[DIN], sc_qc[DIN], sc_lam[DIN], sc_isum[DIN], sc_il[DIN];
    __shared__ float s_cab, s_cgp;
    __shared__ __align__(16) float h[NTRAIN][HSTRIDE];  // {h0..h11, basei, wav, pad2}
    __shared__ __align__(16) float2 bw[NTRAIN];         // {basej, wc}
    __shared__ float red[8][13];
    __shared__ float redg[2][16];       // gp wave partials (waves 2,3)
    __shared__ unsigned int s_last;

    // ---- preload X rows into registers (overlaps with setup latency) ----
    int j0 = 2*lane;
    float xa[12], xb[12], xi[12];
    {
        const float4* xr = (const float4*)(X + j0*DIN);   // rows j0, j0+1 contiguous
        float4 t0 = xr[0], t1 = xr[1], t2 = xr[2], t3 = xr[3], t4 = xr[4], t5 = xr[5];
        xa[0]=t0.x; xa[1]=t0.y; xa[2]=t0.z; xa[3]=t0.w;
        xa[4]=t1.x; xa[5]=t1.y; xa[6]=t1.z; xa[7]=t1.w;
        xa[8]=t2.x; xa[9]=t2.y; xa[10]=t2.z; xa[11]=t2.w;
        xb[0]=t3.x; xb[1]=t3.y; xb[2]=t3.z; xb[3]=t3.w;
        xb[4]=t4.x; xb[5]=t4.y; xb[6]=t4.z; xb[7]=t4.w;
        xb[8]=t5.x; xb[9]=t5.y; xb[10]=t5.z; xb[11]=t5.w;
    }
    if (tid < 256) {                   // rows for pair h (0..127) and gp points (128..255)
        int rowi = tid & 127;
        const float4* xr = (const float4*)(X + rowi*DIN);
        float4 t0 = xr[0], t1 = xr[1], t2 = xr[2];
        xi[0]=t0.x; xi[1]=t0.y; xi[2]=t0.z; xi[3]=t0.w;
        xi[4]=t1.x; xi[5]=t1.y; xi[6]=t1.z; xi[7]=t1.w;
        xi[8]=t2.x; xi[9]=t2.y; xi[10]=t2.z; xi[11]=t2.w;
    }

    // ---- stage 0: joint_var + per-dim scalars ----
    if (tid < 144) {
        int r = tid / 12, cl = tid % 12;
        float v;
        if (r < OBS && cl < OBS) {
            v = s_x[(b*OBS+r)*OBS + cl];
        } else if (r < OBS) {
            v = 0.f;
            #pragma unroll
            for (int k = 0; k < OBS; k++)
                v += s_x[(b*OBS+r)*OBS+k] * c_xu[(b*OBS+k)*ACT + (cl-OBS)];
        } else if (cl < OBS) {
            v = 0.f;
            #pragma unroll
            for (int k = 0; k < OBS; k++)
                v += s_x[(b*OBS+cl)*OBS+k] * c_xu[(b*OBS+k)*ACT + (r-OBS)];
        } else {
            v = s_u[(b*ACT+r-OBS)*ACT + (cl-OBS)];
        }
        jvs[tid] = v;
    } else if (tid >= 160 && tid < 172) {
        int d = tid - 160;
        mu[d] = (d < OBS) ? m_x[b*OBS+d] : m_u[b*ACT+d-OBS];
    } else if (tid >= 192 && tid < 204) {
        int d = tid - 192;
        float la = ls[a*DIN+d]; la *= la;
        float lc = ls[c*DIN+d]; lc *= lc;
        float ia = 1.f/la, ic = 1.f/lc;
        float is = ia + ic;
        float L  = 1.f/is;
        sc_wsum[d] = 1.f/(la+lc);
        sc_iA[d] = L*ia;       // r_i = iA*x_i - mu
        sc_qc[d] = L*ic;       // q_j = qc*x_j
        sc_lam[d] = L;
        sc_isum[d] = is;
    } else if (tid >= 224 && tid < 236) {
        int d = tid - 224;
        sc_il[d] = 1.f / ls[a*DIN+d];   // gp inv lengthscale (e=a; only read when diag)
    }
    __syncthreads();

    // ---- stage 1: dual 12-lane shuffle Gauss-Jordan in wave 0 ----
    // lanes 0..15 (grp 0): pair M = jv + diag(Lam)   [12..15 are padding lanes]
    // lanes 16..27 (grp 1): gp  B = il*jv*il + I
    if (tid < 64 && lane < 28) {
        int grp = lane >> 4;
        int base = grp << 4;
        int r = lane - base;
        int rr = (r < 12) ? r : 0;      // clamp padding lanes' row index
        float row[12];
        if (grp == 0) {
            #pragma unroll
            for (int j = 0; j < 12; j++) row[j] = jvs[rr*12+j];
            row[rr] += sc_lam[rr];
        } else {
            float ir = sc_il[r];
            #pragma unroll
            for (int j = 0; j < 12; j++) row[j] = ir * sc_il[j] * jvs[r*12+j];
            row[r] += 1.f;
        }
        float det = 1.f;
        #pragma unroll
        for (int k = 0; k < 12; k++) {
            float p = __shfl(row[k], base + k);
            float ip = 1.f / p;
            det *= p;
            float prow[12];
            #pragma unroll
            for (int j = 0; j < 12; j++) prow[j] = __shfl(row[j], base + k) * ip;
            if (r == k) {
                #pragma unroll
                for (int j = 0; j < 12; j++) row[j] = prow[j];
                row[k] = ip;
            } else {
                float f = row[k];
                #pragma unroll
                for (int j = 0; j < 12; j++) if (j != k) row[j] -= f * prow[j];
                row[k] = -f * ip;
            }
        }
        if (r < 12) {
            float* W = grp ? Wg : Wl;
            #pragma unroll
            for (int j = 0; j < 12; j++) W[r*12+j] = row[j];
        }
        if (lane == 0) {
            float s = det;                          // det(R)=det(M)*prod(isum)
            #pragma unroll
            for (int d = 0; d < 12; d++) s *= sc_isum[d];
            s_cab = vars[a]*vars[c] / sqrtf(s);
        }
        if (lane == 16) s_cgp = vars[a] / sqrtf(det);
    }
    __syncthreads();

    // ---- stage 2a: pair h/bw on threads 0..127; gp points on threads 128..255 ----
    if (tid < NTRAIN) {
        int t = tid;
        float r[12], q[12]; float e1 = 0.f;
        #pragma unroll
        for (int d = 0; d < 12; d++) {
            r[d] = sc_iA[d]*xi[d] - mu[d];
            q[d] = sc_qc[d]*xi[d];
            e1 += sc_wsum[d]*xi[d]*xi[d];      // shared by i- and j-side
        }
        float hrow[16];
        float alpha = 0.f, bq = 0.f;
        #pragma unroll
        for (int d = 0; d < 12; d++) {
            float u = 0.f, uq = 0.f;
            #pragma unroll
            for (int cl = 0; cl < 12; cl++) {
                float wv = Wl[d*12+cl];
                u  += wv*r[cl];
                uq += wv*q[cl];
            }
            alpha += r[d]*u;
            bq    += q[d]*uq;
            hrow[d] = sc_wsum[d]*xi[d] - u*sc_qc[d];   // folded cross term
        }
        hrow[12] = -0.5f*(e1 + alpha);                 // basei
        hrow[13] = beta[a*NTRAIN+t];                   // wav
        hrow[14] = 0.f; hrow[15] = 0.f;
        float4* hp = (float4*)&h[t][0];
        hp[0] = make_float4(hrow[0],hrow[1],hrow[2],hrow[3]);
        hp[1] = make_float4(hrow[4],hrow[5],hrow[6],hrow[7]);
        hp[2] = make_float4(hrow[8],hrow[9],hrow[10],hrow[11]);
        hp[3] = make_float4(hrow[12],hrow[13],hrow[14],hrow[15]);
        bw[t] = make_float2(-0.5f*(e1 + bq), beta[c*NTRAIN+t]);
    } else if (diag && tid < 256) {
        int n = tid - 128;
        float iN[12], tv[12];
        #pragma unroll
        for (int d = 0; d < 12; d++) iN[d] = (xi[d] - mu[d]) * sc_il[d];
        float qq = 0.f;
        #pragma unroll
        for (int d = 0; d < 12; d++) {
            float u = 0.f;
            #pragma unroll
            for (int cl = 0; cl < 12; cl++) u += Wg[d*12+cl]*iN[cl];
            tv[d] = u; qq += iN[d]*u;
        }
        float lb = __expf(-0.5f*qq) * beta[a*NTRAIN+n];
        float vals[13];
        vals[0] = lb;
        #pragma unroll
        for (int d = 0; d < 12; d++) vals[1+d] = tv[d]*sc_il[d]*lb;
        #pragma unroll
        for (int v = 0; v < 13; v++)
            #pragma unroll
            for (int off = 32; off >= 1; off >>= 1) vals[v] += __shfl_xor(vals[v], off, 64);
        if (lane == 0) {
            #pragma unroll
            for (int v = 0; v < 13; v++) redg[w-2][v] = vals[v];  // waves 2,3
        }
    }
    __syncthreads();

    // ---- stage 2b: sweep. lane owns j0=2l, 2l+1; wave w handles i = w + 8k. ----
    float4 bwv = ((const float4*)bw)[lane];   // {basej0, wc0, basej1, wc1}
    float basej0 = bwv.x, wc0 = bwv.y, basej1 = bwv.z, wc1 = bwv.w;
    float am0 = 0.f, am1 = 0.f, at0 = 0.f, at1 = 0.f;
    const float2* Kb = (const float2*)(invK + a*NTRAIN*NTRAIN);
    #pragma unroll 4
    for (int k = 0; k < 16; k++) {
        int i = w + 8*k;                         // wave-uniform -> LDS broadcast
        const float4* hp = (const float4*)&h[i][0];
        float4 h0 = hp[0], h1 = hp[1], h2 = hp[2];
        float2 h3 = *(const float2*)&h[i][12];   // {basei, wav}
        float sA0 = fmaf(h0.x,xa[0], fmaf(h0.y,xa[1], fmaf(h0.z,xa[2], h0.w*xa[3])));
        float sB0 = fmaf(h1.x,xa[4], fmaf(h1.y,xa[5], fmaf(h1.z,xa[6], h1.w*xa[7])));
        float sC0 = fmaf(h2.x,xa[8], fmaf(h2.y,xa[9], fmaf(h2.z,xa[10], h2.w*xa[11])));
        float sA1 = fmaf(h0.x,xb[0], fmaf(h0.y,xb[1], fmaf(h0.z,xb[2], h0.w*xb[3])));
        float sB1 = fmaf(h1.x,xb[4], fmaf(h1.y,xb[5], fmaf(h1.z,xb[6], h1.w*xb[7])));
        float sC1 = fmaf(h2.x,xb[8], fmaf(h2.y,xb[9], fmaf(h2.z,xb[10], h2.w*xb[11])));
        float e0  = __expf(sA0 + sB0 + sC0 + h3.x + basej0);
        float e1v = __expf(sA1 + sB1 + sC1 + h3.x + basej1);
        am0 = fmaf(h3.y, e0, am0);
        am1 = fmaf(h3.y, e1v, am1);
        if (diag) {
            float2 kv = Kb[i*64 + lane];          // Ka[i][2l], Ka[i][2l+1]
            at0 = fmaf(kv.x, e0, at0);
            at1 = fmaf(kv.y, e1v, at1);
        }
    }
    float accm = am0*wc0 + am1*wc1;
    float acct = at0 + at1;
    #pragma unroll
    for (int off = 32; off >= 1; off >>= 1) {
        accm += __shfl_xor(accm, off, 64);
        acct += __shfl_xor(acct, off, 64);
    }
    if (lane == 0) { red[w][0] = accm; red[w][1] = acct; }
    __syncthreads();
    if (tid == 0) {
        float m = 0.f, t = 0.f;
        #pragma unroll
        for (int v = 0; v < 8; v++) { m += red[v][0]; t += red[v][1]; }
        m *= s_cab; t *= s_cab;
        ws[WS_MN + b*64 + a*8 + c] = m;
        ws[WS_MN + b*64 + c*8 + a] = m;          // exact symmetry
        if (diag) ws[WS_TR + b*8 + a] = t;
    } else if (tid == 64 && diag) {
        float cn = s_cgp;
        ws[WS_PM + b*OBS + a] = cn*(redg[0][0]+redg[1][0]);
        #pragma unroll
        for (int d = 0; d < 12; d++)
            ws[WS_CC + (b*DIN+d)*OBS + a] = cn*(redg[0][1+d]+redg[1][1+d]);
    }
    __syncthreads();   // all this block's ws stores complete (vmcnt drained)

    // ---- last-block-done: device-scope counter; winner runs the epilogue ----
    if (tid == 0) {
        __threadfence();   // publish this block's (whole CU/XCD L2) ws writes
        unsigned int old = __hip_atomic_fetch_add(
            (unsigned int*)(ws + WS_CNT), 1u,
            __ATOMIC_ACQ_REL, __HIP_MEMORY_SCOPE_AGENT);
        s_last = (old == NBLK - 1) ? 1u : 0u;
    }
    __syncthreads();

    if (s_last) {
        __threadfence();   // acquire: invalidate stale cached ws lines
        // wave w handles batch bb=w; reuse h[] as epilogue scratch
        float* epiSx = &h[0][0];            // 512 floats: s_x for all batches
        float* epiPm = &h[64][0];           // 64 floats: pred_mean
        epiSx[tid] = s_x[tid];              // s_x is exactly 8*8*8 = 512 floats
        if (tid < 64) epiPm[tid] = ws[WS_PM + tid];
        __syncthreads();
        int bb = w, t = lane;
        int r = t >> 3, cl = t & 7;
        const float* cc  = ws + WS_CC + bb*DIN*OBS;
        const float* mn  = ws + WS_MN + bb*64;
        const float* tr  = ws + WS_TR + bb*OBS;
        const float* sxs = epiSx + bb*64;
        const float* pm8 = epiPm + bb*8;
        float P = mn[r*8 + cl];
        if (r == cl) P += vars[r] - tr[r] + noises[r];
        P -= pm8[r]*pm8[cl];
        float cxf = 0.f, cxfT = 0.f;
        #pragma unroll
        for (int d = 0; d < 8; d++) {
            cxf  += sxs[r*8+d]  * cc[d*8+cl];
            cxfT += sxs[cl*8+d] * cc[d*8+r];
        }
        #pragma unroll
        for (int d = 0; d < 4; d++) {
            float jr = 0.f, jc = 0.f;
            #pragma unroll
            for (int k = 0; k < 8; k++) {
                float cx = c_xu[(bb*OBS+k)*ACT + d];
                jr += sxs[r*8+k]  * cx;
                jc += sxs[cl*8+k] * cx;
            }
            cxf  += jr * cc[(8+d)*8 + cl];
            cxfT += jc * cc[(8+d)*8 + r];
        }
        float S = sxs[r*8+cl] + P + cxf + cxfT;
        if (r == cl) S += 1e-8f;
        out[64 + bb*64 + t] = S;                         // s_out
        if (t < OBS) out[bb*OBS + t] = m_x[bb*OBS + t] + pm8[t];   // m_out
    }
}

// ---------------------------------------------------------------------------
extern "C" void kernel_launch(void* const* d_in, const int* in_sizes, int n_in,
                              void* d_out, int out_size, void* d_ws, size_t ws_size,
                              hipStream_t stream) {
    const float* m_x    = (const float*)d_in[0];
    const float* s_x    = (const float*)d_in[1];
    const float* m_u    = (const float*)d_in[2];
    const float* s_u    = (const float*)d_in[3];
    const float* c_xu   = (const float*)d_in[4];
    const float* X      = (const float*)d_in[5];
    const float* ls     = (const float*)d_in[6];
    const float* vars   = (const float*)d_in[7];
    const float* noises = (const float*)d_in[8];
    const float* invK   = (const float*)d_in[9];
    const float* beta   = (const float*)d_in[10];
    float* out = (float*)d_out;
    float* ws  = (float*)d_ws;

    // zero the completion counter (ws is re-poisoned by the harness each iter)
    hipMemsetAsync((char*)d_ws + WS_CNT*sizeof(float), 0, 4, stream);
    k_all<<<NBLK, THREADS, 0, stream>>>(m_x, s_x, m_u, s_u, c_xu, X, ls, vars,
                                        noises, beta, invK, ws, out);
}

// Round 3
// 96.404 us; speedup vs baseline: 1.1058x; 1.1058x over previous
//
#include <hip/hip_runtime.h>
#include <math.h>

#define OBS 8
#define ACT 4
#define DIN 12
#define NTRAIN 128
#define BATCH 8
#define NPAIR 36               // triangle a<=c
#define NBLK (BATCH*NPAIR)     // 288 blocks (gp tasks merged into diag blocks)
#define THREADS 512
#define HSTRIDE 16             // floats per h row (64B; 2-way write alias = free)

// ws layout (floats)
#define WS_PM  0               // 64   pred_mean[b][e]
#define WS_CC  64              // 768  cross_cov[b][d][e]
#define WS_MN  832             // 512  main[b][a][c]
#define WS_TR  1344            // 64   trace[b][e]
#define WS_CNT 1536            // 1    completion counter (memset to 0 per launch)

// Device-coherent (agent-scope, cache-bypassing) ws accesses: no L2 flush or
// invalidate needed anywhere — publishes go straight to the coherent point.
#define WS_ST(p, v) __hip_atomic_store((p), (v), __ATOMIC_RELAXED, __HIP_MEMORY_SCOPE_AGENT)
#define WS_LD(p)    __hip_atomic_load((p), __ATOMIC_RELAXED, __HIP_MEMORY_SCOPE_AGENT)

// ---------------------------------------------------------------------------
// Single kernel: 288 blocks x 512 threads (8 waves), plain launch.
// Every block is a pair task (a<=c). Diag blocks (a==c) additionally run the
// gp predictive task for e=a (dual shuffle-GJ in wave 0; gp point work on the
// otherwise-idle waves 2..3). Epilogue: last-block-done — RELAXED agent-scope
// counter; all ws publishes are RELAXED agent-scope stores drained by the
// __syncthreads() (vmcnt(0)) that precedes the counter bump, so no fences /
// cache writebacks are needed. Winner block runs the former k_final for all
// 8 batches (wave w <-> batch w), staging ws through LDS in one round-trip.
// __launch_bounds__(512) only: DO NOT add a min-waves floor — (512,4) capped
// VGPR at 64 and spilled xa/xb/xi to scratch (round-2: WRITE_SIZE 2.5 MB,
// VALUBusy 6.6%, k_all 48us).
// ---------------------------------------------------------------------------
__global__ void __launch_bounds__(THREADS) k_all(
    const float* __restrict__ m_x, const float* __restrict__ s_x,
    const float* __restrict__ m_u, const float* __restrict__ s_u,
    const float* __restrict__ c_xu, const float* __restrict__ X,
    const float* __restrict__ ls, const float* __restrict__ vars,
    const float* __restrict__ noises, const float* __restrict__ beta,
    const float* __restrict__ invK, float* __restrict__ ws,
    float* __restrict__ out)
{
    int blk = blockIdx.x, tid = threadIdx.x;
    int lane = tid & 63, w = tid >> 6;
    int b = blk / NPAIR;
    int rem = blk % NPAIR;
    int a = 0;
    while (rem >= OBS - a) { rem -= OBS - a; a++; }
    int c = a + rem;
    bool diag = (a == c);

    __shared__ float jvs[144];          // joint_var
    __shared__ float Wl[144];           // pair M-inverse
    __shared__ float Wg[144];           // gp B-inverse (diag blocks)
    __shared__ float mu[DIN];
    __shared__ float sc_wsum[DIN], sc_iA[DIN], sc_qc[DIN], sc_lam[DIN], sc_isum[DIN], sc_il[DIN];
    __shared__ float s_cab, s_cgp;
    __shared__ __align__(16) float h[NTRAIN][HSTRIDE];  // {h0..h11, basei, wav, pad2}
    __shared__ __align__(16) float2 bw[NTRAIN];         // {basej, wc}
    __shared__ float red[8][13];
    __shared__ float redg[2][16];       // gp wave partials (waves 2,3)
    __shared__ unsigned int s_last;

    // ---- preload X rows into registers (overlaps with setup latency) ----
    int j0 = 2*lane;
    float xa[12], xb[12], xi[12];
    {
        const float4* xr = (const float4*)(X + j0*DIN);   // rows j0, j0+1 contiguous
        float4 t0 = xr[0], t1 = xr[1], t2 = xr[2], t3 = xr[3], t4 = xr[4], t5 = xr[5];
        xa[0]=t0.x; xa[1]=t0.y; xa[2]=t0.z; xa[3]=t0.w;
        xa[4]=t1.x; xa[5]=t1.y; xa[6]=t1.z; xa[7]=t1.w;
        xa[8]=t2.x; xa[9]=t2.y; xa[10]=t2.z; xa[11]=t2.w;
        xb[0]=t3.x; xb[1]=t3.y; xb[2]=t3.z; xb[3]=t3.w;
        xb[4]=t4.x; xb[5]=t4.y; xb[6]=t4.z; xb[7]=t4.w;
        xb[8]=t5.x; xb[9]=t5.y; xb[10]=t5.z; xb[11]=t5.w;
    }
    if (tid < 256) {                   // rows for pair h (0..127) and gp points (128..255)
        int rowi = tid & 127;
        const float4* xr = (const float4*)(X + rowi*DIN);
        float4 t0 = xr[0], t1 = xr[1], t2 = xr[2];
        xi[0]=t0.x; xi[1]=t0.y; xi[2]=t0.z; xi[3]=t0.w;
        xi[4]=t1.x; xi[5]=t1.y; xi[6]=t1.z; xi[7]=t1.w;
        xi[8]=t2.x; xi[9]=t2.y; xi[10]=t2.z; xi[11]=t2.w;
    }

    // ---- stage 0: joint_var + per-dim scalars ----
    if (tid < 144) {
        int r = tid / 12, cl = tid % 12;
        float v;
        if (r < OBS && cl < OBS) {
            v = s_x[(b*OBS+r)*OBS + cl];
        } else if (r < OBS) {
            v = 0.f;
            #pragma unroll
            for (int k = 0; k < OBS; k++)
                v += s_x[(b*OBS+r)*OBS+k] * c_xu[(b*OBS+k)*ACT + (cl-OBS)];
        } else if (cl < OBS) {
            v = 0.f;
            #pragma unroll
            for (int k = 0; k < OBS; k++)
                v += s_x[(b*OBS+cl)*OBS+k] * c_xu[(b*OBS+k)*ACT + (r-OBS)];
        } else {
            v = s_u[(b*ACT+r-OBS)*ACT + (cl-OBS)];
        }
        jvs[tid] = v;
    } else if (tid >= 160 && tid < 172) {
        int d = tid - 160;
        mu[d] = (d < OBS) ? m_x[b*OBS+d] : m_u[b*ACT+d-OBS];
    } else if (tid >= 192 && tid < 204) {
        int d = tid - 192;
        float la = ls[a*DIN+d]; la *= la;
        float lc = ls[c*DIN+d]; lc *= lc;
        float ia = 1.f/la, ic = 1.f/lc;
        float is = ia + ic;
        float L  = 1.f/is;
        sc_wsum[d] = 1.f/(la+lc);
        sc_iA[d] = L*ia;       // r_i = iA*x_i - mu
        sc_qc[d] = L*ic;       // q_j = qc*x_j
        sc_lam[d] = L;
        sc_isum[d] = is;
    } else if (tid >= 224 && tid < 236) {
        int d = tid - 224;
        sc_il[d] = 1.f / ls[a*DIN+d];   // gp inv lengthscale (e=a; only read when diag)
    }
    __syncthreads();

    // ---- stage 1: dual 12-lane shuffle Gauss-Jordan in wave 0 ----
    // lanes 0..15 (grp 0): pair M = jv + diag(Lam)   [12..15 are padding lanes]
    // lanes 16..27 (grp 1): gp  B = il*jv*il + I
    if (tid < 64 && lane < 28) {
        int grp = lane >> 4;
        int base = grp << 4;
        int r = lane - base;
        int rr = (r < 12) ? r : 0;      // clamp padding lanes' row index
        float row[12];
        if (grp == 0) {
            #pragma unroll
            for (int j = 0; j < 12; j++) row[j] = jvs[rr*12+j];
            row[rr] += sc_lam[rr];
        } else {
            float ir = sc_il[r];
            #pragma unroll
            for (int j = 0; j < 12; j++) row[j] = ir * sc_il[j] * jvs[r*12+j];
            row[r] += 1.f;
        }
        float det = 1.f;
        #pragma unroll
        for (int k = 0; k < 12; k++) {
            float p = __shfl(row[k], base + k);
            float ip = 1.f / p;
            det *= p;
            float prow[12];
            #pragma unroll
            for (int j = 0; j < 12; j++) prow[j] = __shfl(row[j], base + k) * ip;
            if (r == k) {
                #pragma unroll
                for (int j = 0; j < 12; j++) row[j] = prow[j];
                row[k] = ip;
            } else {
                float f = row[k];
                #pragma unroll
                for (int j = 0; j < 12; j++) if (j != k) row[j] -= f * prow[j];
                row[k] = -f * ip;
            }
        }
        if (r < 12) {
            float* W = grp ? Wg : Wl;
            #pragma unroll
            for (int j = 0; j < 12; j++) W[r*12+j] = row[j];
        }
        if (lane == 0) {
            float s = det;                          // det(R)=det(M)*prod(isum)
            #pragma unroll
            for (int d = 0; d < 12; d++) s *= sc_isum[d];
            s_cab = vars[a]*vars[c] / sqrtf(s);
        }
        if (lane == 16) s_cgp = vars[a] / sqrtf(det);
    }
    __syncthreads();

    // ---- stage 2a: pair h/bw on threads 0..127; gp points on threads 128..255 ----
    if (tid < NTRAIN) {
        int t = tid;
        float r[12], q[12]; float e1 = 0.f;
        #pragma unroll
        for (int d = 0; d < 12; d++) {
            r[d] = sc_iA[d]*xi[d] - mu[d];
            q[d] = sc_qc[d]*xi[d];
            e1 += sc_wsum[d]*xi[d]*xi[d];      // shared by i- and j-side
        }
        float hrow[16];
        float alpha = 0.f, bq = 0.f;
        #pragma unroll
        for (int d = 0; d < 12; d++) {
            float u = 0.f, uq = 0.f;
            #pragma unroll
            for (int cl = 0; cl < 12; cl++) {
                float wv = Wl[d*12+cl];
                u  += wv*r[cl];
                uq += wv*q[cl];
            }
            alpha += r[d]*u;
            bq    += q[d]*uq;
            hrow[d] = sc_wsum[d]*xi[d] - u*sc_qc[d];   // folded cross term
        }
        hrow[12] = -0.5f*(e1 + alpha);                 // basei
        hrow[13] = beta[a*NTRAIN+t];                   // wav
        hrow[14] = 0.f; hrow[15] = 0.f;
        float4* hp = (float4*)&h[t][0];
        hp[0] = make_float4(hrow[0],hrow[1],hrow[2],hrow[3]);
        hp[1] = make_float4(hrow[4],hrow[5],hrow[6],hrow[7]);
        hp[2] = make_float4(hrow[8],hrow[9],hrow[10],hrow[11]);
        hp[3] = make_float4(hrow[12],hrow[13],hrow[14],hrow[15]);
        bw[t] = make_float2(-0.5f*(e1 + bq), beta[c*NTRAIN+t]);
    } else if (diag && tid < 256) {
        int n = tid - 128;
        float iN[12], tv[12];
        #pragma unroll
        for (int d = 0; d < 12; d++) iN[d] = (xi[d] - mu[d]) * sc_il[d];
        float qq = 0.f;
        #pragma unroll
        for (int d = 0; d < 12; d++) {
            float u = 0.f;
            #pragma unroll
            for (int cl = 0; cl < 12; cl++) u += Wg[d*12+cl]*iN[cl];
            tv[d] = u; qq += iN[d]*u;
        }
        float lb = __expf(-0.5f*qq) * beta[a*NTRAIN+n];
        float vals[13];
        vals[0] = lb;
        #pragma unroll
        for (int d = 0; d < 12; d++) vals[1+d] = tv[d]*sc_il[d]*lb;
        #pragma unroll
        for (int v = 0; v < 13; v++)
            #pragma unroll
            for (int off = 32; off >= 1; off >>= 1) vals[v] += __shfl_xor(vals[v], off, 64);
        if (lane == 0) {
            #pragma unroll
            for (int v = 0; v < 13; v++) redg[w-2][v] = vals[v];  // waves 2,3
        }
    }
    __syncthreads();

    // ---- stage 2b: sweep. lane owns j0=2l, 2l+1; wave w handles i = w + 8k. ----
    float4 bwv = ((const float4*)bw)[lane];   // {basej0, wc0, basej1, wc1}
    float basej0 = bwv.x, wc0 = bwv.y, basej1 = bwv.z, wc1 = bwv.w;
    float am0 = 0.f, am1 = 0.f, at0 = 0.f, at1 = 0.f;
    const float2* Kb = (const float2*)(invK + a*NTRAIN*NTRAIN);
    #pragma unroll 4
    for (int k = 0; k < 16; k++) {
        int i = w + 8*k;                         // wave-uniform -> LDS broadcast
        const float4* hp = (const float4*)&h[i][0];
        float4 h0 = hp[0], h1 = hp[1], h2 = hp[2];
        float2 h3 = *(const float2*)&h[i][12];   // {basei, wav}
        float sA0 = fmaf(h0.x,xa[0], fmaf(h0.y,xa[1], fmaf(h0.z,xa[2], h0.w*xa[3])));
        float sB0 = fmaf(h1.x,xa[4], fmaf(h1.y,xa[5], fmaf(h1.z,xa[6], h1.w*xa[7])));
        float sC0 = fmaf(h2.x,xa[8], fmaf(h2.y,xa[9], fmaf(h2.z,xa[10], h2.w*xa[11])));
        float sA1 = fmaf(h0.x,xb[0], fmaf(h0.y,xb[1], fmaf(h0.z,xb[2], h0.w*xb[3])));
        float sB1 = fmaf(h1.x,xb[4], fmaf(h1.y,xb[5], fmaf(h1.z,xb[6], h1.w*xb[7])));
        float sC1 = fmaf(h2.x,xb[8], fmaf(h2.y,xb[9], fmaf(h2.z,xb[10], h2.w*xb[11])));
        float e0  = __expf(sA0 + sB0 + sC0 + h3.x + basej0);
        float e1v = __expf(sA1 + sB1 + sC1 + h3.x + basej1);
        am0 = fmaf(h3.y, e0, am0);
        am1 = fmaf(h3.y, e1v, am1);
        if (diag) {
            float2 kv = Kb[i*64 + lane];          // Ka[i][2l], Ka[i][2l+1]
            at0 = fmaf(kv.x, e0, at0);
            at1 = fmaf(kv.y, e1v, at1);
        }
    }
    float accm = am0*wc0 + am1*wc1;
    float acct = at0 + at1;
    #pragma unroll
    for (int off = 32; off >= 1; off >>= 1) {
        accm += __shfl_xor(accm, off, 64);
        acct += __shfl_xor(acct, off, 64);
    }
    if (lane == 0) { red[w][0] = accm; red[w][1] = acct; }
    __syncthreads();

    // ---- publish results to ws via device-coherent stores ----
    if (tid == 0) {
        float m = 0.f, t = 0.f;
        #pragma unroll
        for (int v = 0; v < 8; v++) { m += red[v][0]; t += red[v][1]; }
        m *= s_cab; t *= s_cab;
        WS_ST(&ws[WS_MN + b*64 + a*8 + c], m);
        WS_ST(&ws[WS_MN + b*64 + c*8 + a], m);   // exact symmetry
        if (diag) WS_ST(&ws[WS_TR + b*8 + a], t);
    } else if (tid == 64 && diag) {
        float cn = s_cgp;
        WS_ST(&ws[WS_PM + b*OBS + a], cn*(redg[0][0]+redg[1][0]));
        #pragma unroll
        for (int d = 0; d < 12; d++)
            WS_ST(&ws[WS_CC + (b*DIN+d)*OBS + a], cn*(redg[0][1+d]+redg[1][1+d]));
    }
    __syncthreads();   // vmcnt(0): coherent publishes complete before the count

    // ---- last-block-done: relaxed agent counter; winner runs the epilogue ----
    if (tid == 0) {
        unsigned int old = __hip_atomic_fetch_add(
            (unsigned int*)(ws + WS_CNT), 1u,
            __ATOMIC_RELAXED, __HIP_MEMORY_SCOPE_AGENT);
        s_last = (old == NBLK - 1) ? 1u : 0u;
    }
    __syncthreads();

    if (s_last) {
        // Stage all ws data into LDS (reuse h[]) with one parallel round-trip
        // of coherent loads; then wave w computes batch bb=w from LDS.
        float* epiSx = &h[0][0];             // 512 floats  h[0..32)
        float* epiCc = &h[32][0];            // 768 floats  h[32..80)
        float* epiMn = &h[80][0];            // 512 floats  h[80..112)
        float* epiPm = &h[112][0];           // 64  floats  h[112..116)
        float* epiTr = &h[116][0];           // 64  floats  h[116..120)
        epiSx[tid] = s_x[tid];               // s_x is exactly 8*8*8 = 512 floats
        epiCc[tid] = WS_LD(&ws[WS_CC + tid]);
        if (tid < 256) epiCc[512 + tid] = WS_LD(&ws[WS_CC + 512 + tid]);
        epiMn[tid] = WS_LD(&ws[WS_MN + tid]);
        if (tid < 64) {
            epiPm[tid] = WS_LD(&ws[WS_PM + tid]);
            epiTr[tid] = WS_LD(&ws[WS_TR + tid]);
        }
        __syncthreads();
        int bb = w, t = lane;
        int r = t >> 3, cl = t & 7;
        const float* sxs = epiSx + bb*64;
        const float* pm8 = epiPm + bb*8;
        const float* mnb = epiMn + bb*64;
        const float* trb = epiTr + bb*8;
        const float* ccb = epiCc + bb*DIN*OBS;
        float P = mnb[r*8 + cl];
        if (r == cl) P += vars[r] - trb[r] + noises[r];
        P -= pm8[r]*pm8[cl];
        float cxf = 0.f, cxfT = 0.f;
        #pragma unroll
        for (int d = 0; d < 8; d++) {
            cxf  += sxs[r*8+d]  * ccb[d*8+cl];
            cxfT += sxs[cl*8+d] * ccb[d*8+r];
        }
        #pragma unroll
        for (int d = 0; d < 4; d++) {
            float jr = 0.f, jc = 0.f;
            #pragma unroll
            for (int k = 0; k < 8; k++) {
                float cx = c_xu[(bb*OBS+k)*ACT + d];
                jr += sxs[r*8+k]  * cx;
                jc += sxs[cl*8+k] * cx;
            }
            cxf  += jr * ccb[(8+d)*8 + cl];
            cxfT += jc * ccb[(8+d)*8 + r];
        }
        float S = sxs[r*8+cl] + P + cxf + cxfT;
        if (r == cl) S += 1e-8f;
        out[64 + bb*64 + t] = S;                         // s_out
        if (t < OBS) out[bb*OBS + t] = m_x[bb*OBS + t] + pm8[t];   // m_out
    }
}

// ---------------------------------------------------------------------------
extern "C" void kernel_launch(void* const* d_in, const int* in_sizes, int n_in,
                              void* d_out, int out_size, void* d_ws, size_t ws_size,
                              hipStream_t stream) {
    const float* m_x    = (const float*)d_in[0];
    const float* s_x    = (const float*)d_in[1];
    const float* m_u    = (const float*)d_in[2];
    const float* s_u    = (const float*)d_in[3];
    const float* c_xu   = (const float*)d_in[4];
    const float* X      = (const float*)d_in[5];
    const float* ls     = (const float*)d_in[6];
    const float* vars   = (const float*)d_in[7];
    const float* noises = (const float*)d_in[8];
    const float* invK   = (const float*)d_in[9];
    const float* beta   = (const float*)d_in[10];
    float* out = (float*)d_out;
    float* ws  = (float*)d_ws;

    // zero the completion counter (ws is re-poisoned by the harness each iter)
    hipMemsetAsync((char*)d_ws + WS_CNT*sizeof(float), 0, 4, stream);
    k_all<<<NBLK, THREADS, 0, stream>>>(m_x, s_x, m_u, s_u, c_xu, X, ls, vars,
                                        noises, beta, invK, ws, out);
}

// Round 4
// 92.913 us; speedup vs baseline: 1.1473x; 1.0376x over previous
//
#include <hip/hip_runtime.h>
#include <math.h>

#define OBS 8
#define ACT 4
#define DIN 12
#define NTRAIN 128
#define BATCH 8
#define NPAIR 36               // triangle a<=c
#define NBLK (BATCH*NPAIR)     // 288 blocks (gp tasks merged into diag blocks)
#define THREADS 512
#define HSTRIDE 16             // floats per h row (64B; 2-way write alias = free)

// ws layout (floats)
#define WS_PM  0               // 64   pred_mean[b][e]
#define WS_CC  64              // 768  cross_cov[b][d][e]
#define WS_MN  832             // 512  main[b][a][c]
#define WS_TR  1344            // 64   trace[b][e]

// ---------------------------------------------------------------------------
// Main kernel: 288 blocks x 512 threads (8 waves), plain launch.
// Every block is a pair task (a<=c). Diag blocks (a==c) additionally run the
// gp predictive task for e=a: its 12x12 B-inverse is computed by lanes 16..27
// of wave 0 in the SAME shuffle-GJ pass that lanes 0..11 use for M, and its
// per-point work runs on waves 2..3 (idle during stage 2a otherwise).
// Results go to ws via plain stores; the separate k_final dispatch gives
// device-wide visibility for free (kernel-boundary release). NOTE (round-2/3
// lessons): do NOT add a min-waves __launch_bounds__ floor (spills xa/xb/xi,
// 2.5MB scratch traffic); do NOT replace k_final with an atomic last-block
// epilogue (memset dispatch + coherent-publish tail cost ~5us net).
// ---------------------------------------------------------------------------
__global__ void __launch_bounds__(THREADS) k_fused(
    const float* __restrict__ m_x, const float* __restrict__ s_x,
    const float* __restrict__ m_u, const float* __restrict__ s_u,
    const float* __restrict__ c_xu, const float* __restrict__ X,
    const float* __restrict__ ls, const float* __restrict__ vars,
    const float* __restrict__ beta, const float* __restrict__ invK,
    float* __restrict__ ws)
{
    int blk = blockIdx.x, tid = threadIdx.x;
    int lane = tid & 63, w = tid >> 6;
    int b = blk / NPAIR;
    int rem = blk % NPAIR;
    int a = 0;
    while (rem >= OBS - a) { rem -= OBS - a; a++; }
    int c = a + rem;
    bool diag = (a == c);

    __shared__ float jvs[144];          // joint_var
    __shared__ float Wl[144];           // pair M-inverse
    __shared__ float Wg[144];           // gp B-inverse (diag blocks)
    __shared__ float mu[DIN];
    __shared__ float sc_wsum[DIN], sc_iA[DIN], sc_qc[DIN], sc_lam[DIN], sc_isum[DIN], sc_il[DIN];
    __shared__ float s_cab, s_cgp;
    __shared__ __align__(16) float h[NTRAIN][HSTRIDE];  // {h0..h11, basei, wav, pad2}
    __shared__ __align__(16) float2 bw[NTRAIN];         // {basej, wc}
    __shared__ float red[8][13];
    __shared__ float redg[2][16];       // gp wave partials (waves 2,3)

    // ---- preload X rows into registers (overlaps with setup latency) ----
    int j0 = 2*lane;
    float xa[12], xb[12], xi[12];
    {
        const float4* xr = (const float4*)(X + j0*DIN);   // rows j0, j0+1 contiguous
        float4 t0 = xr[0], t1 = xr[1], t2 = xr[2], t3 = xr[3], t4 = xr[4], t5 = xr[5];
        xa[0]=t0.x; xa[1]=t0.y; xa[2]=t0.z; xa[3]=t0.w;
        xa[4]=t1.x; xa[5]=t1.y; xa[6]=t1.z; xa[7]=t1.w;
        xa[8]=t2.x; xa[9]=t2.y; xa[10]=t2.z; xa[11]=t2.w;
        xb[0]=t3.x; xb[1]=t3.y; xb[2]=t3.z; xb[3]=t3.w;
        xb[4]=t4.x; xb[5]=t4.y; xb[6]=t4.z; xb[7]=t4.w;
        xb[8]=t5.x; xb[9]=t5.y; xb[10]=t5.z; xb[11]=t5.w;
    }
    if (tid < 256) {                   // rows for pair h (0..127) and gp points (128..255)
        int rowi = tid & 127;
        const float4* xr = (const float4*)(X + rowi*DIN);
        float4 t0 = xr[0], t1 = xr[1], t2 = xr[2];
        xi[0]=t0.x; xi[1]=t0.y; xi[2]=t0.z; xi[3]=t0.w;
        xi[4]=t1.x; xi[5]=t1.y; xi[6]=t1.z; xi[7]=t1.w;
        xi[8]=t2.x; xi[9]=t2.y; xi[10]=t2.z; xi[11]=t2.w;
    }

    // ---- stage 0: joint_var + per-dim scalars ----
    if (tid < 144) {
        int r = tid / 12, cl = tid % 12;
        float v;
        if (r < OBS && cl < OBS) {
            v = s_x[(b*OBS+r)*OBS + cl];
        } else if (r < OBS) {
            v = 0.f;
            #pragma unroll
            for (int k = 0; k < OBS; k++)
                v += s_x[(b*OBS+r)*OBS+k] * c_xu[(b*OBS+k)*ACT + (cl-OBS)];
        } else if (cl < OBS) {
            v = 0.f;
            #pragma unroll
            for (int k = 0; k < OBS; k++)
                v += s_x[(b*OBS+cl)*OBS+k] * c_xu[(b*OBS+k)*ACT + (r-OBS)];
        } else {
            v = s_u[(b*ACT+r-OBS)*ACT + (cl-OBS)];
        }
        jvs[tid] = v;
    } else if (tid >= 160 && tid < 172) {
        int d = tid - 160;
        mu[d] = (d < OBS) ? m_x[b*OBS+d] : m_u[b*ACT+d-OBS];
    } else if (tid >= 192 && tid < 204) {
        int d = tid - 192;
        float la = ls[a*DIN+d]; la *= la;
        float lc = ls[c*DIN+d]; lc *= lc;
        float ia = 1.f/la, ic = 1.f/lc;
        float is = ia + ic;
        float L  = 1.f/is;
        sc_wsum[d] = 1.f/(la+lc);
        sc_iA[d] = L*ia;       // r_i = iA*x_i - mu
        sc_qc[d] = L*ic;       // q_j = qc*x_j
        sc_lam[d] = L;
        sc_isum[d] = is;
    } else if (tid >= 224 && tid < 236) {
        int d = tid - 224;
        sc_il[d] = 1.f / ls[a*DIN+d];   // gp inv lengthscale (e=a; only read when diag)
    }
    __syncthreads();

    // ---- stage 1: dual 12-lane shuffle Gauss-Jordan in wave 0 ----
    // lanes 0..15 (grp 0): pair M = jv + diag(Lam)   [12..15 are padding lanes]
    // lanes 16..27 (grp 1): gp  B = il*jv*il + I
    if (tid < 64 && lane < 28) {
        int grp = lane >> 4;
        int base = grp << 4;
        int r = lane - base;
        int rr = (r < 12) ? r : 0;      // clamp padding lanes' row index
        float row[12];
        if (grp == 0) {
            #pragma unroll
            for (int j = 0; j < 12; j++) row[j] = jvs[rr*12+j];
            row[rr] += sc_lam[rr];
        } else {
            float ir = sc_il[r];
            #pragma unroll
            for (int j = 0; j < 12; j++) row[j] = ir * sc_il[j] * jvs[r*12+j];
            row[r] += 1.f;
        }
        float det = 1.f;
        #pragma unroll
        for (int k = 0; k < 12; k++) {
            float p = __shfl(row[k], base + k);
            float ip = 1.f / p;
            det *= p;
            float prow[12];
            #pragma unroll
            for (int j = 0; j < 12; j++) prow[j] = __shfl(row[j], base + k) * ip;
            if (r == k) {
                #pragma unroll
                for (int j = 0; j < 12; j++) row[j] = prow[j];
                row[k] = ip;
            } else {
                float f = row[k];
                #pragma unroll
                for (int j = 0; j < 12; j++) if (j != k) row[j] -= f * prow[j];
                row[k] = -f * ip;
            }
        }
        if (r < 12) {
            float* W = grp ? Wg : Wl;
            #pragma unroll
            for (int j = 0; j < 12; j++) W[r*12+j] = row[j];
        }
        if (lane == 0) {
            float s = det;                          // det(R)=det(M)*prod(isum)
            #pragma unroll
            for (int d = 0; d < 12; d++) s *= sc_isum[d];
            s_cab = vars[a]*vars[c] / sqrtf(s);
        }
        if (lane == 16) s_cgp = vars[a] / sqrtf(det);
    }
    __syncthreads();

    // ---- stage 2a: pair h/bw on threads 0..127; gp points on threads 128..255 ----
    if (tid < NTRAIN) {
        int t = tid;
        float r[12], q[12]; float e1 = 0.f;
        #pragma unroll
        for (int d = 0; d < 12; d++) {
            r[d] = sc_iA[d]*xi[d] - mu[d];
            q[d] = sc_qc[d]*xi[d];
            e1 += sc_wsum[d]*xi[d]*xi[d];      // shared by i- and j-side
        }
        float hrow[16];
        float alpha = 0.f, bq = 0.f;
        #pragma unroll
        for (int d = 0; d < 12; d++) {
            float u = 0.f, uq = 0.f;
            #pragma unroll
            for (int cl = 0; cl < 12; cl++) {
                float wv = Wl[d*12+cl];
                u  += wv*r[cl];
                uq += wv*q[cl];
            }
            alpha += r[d]*u;
            bq    += q[d]*uq;
            hrow[d] = sc_wsum[d]*xi[d] - u*sc_qc[d];   // folded cross term
        }
        hrow[12] = -0.5f*(e1 + alpha);                 // basei
        hrow[13] = beta[a*NTRAIN+t];                   // wav
        hrow[14] = 0.f; hrow[15] = 0.f;
        float4* hp = (float4*)&h[t][0];
        hp[0] = make_float4(hrow[0],hrow[1],hrow[2],hrow[3]);
        hp[1] = make_float4(hrow[4],hrow[5],hrow[6],hrow[7]);
        hp[2] = make_float4(hrow[8],hrow[9],hrow[10],hrow[11]);
        hp[3] = make_float4(hrow[12],hrow[13],hrow[14],hrow[15]);
        bw[t] = make_float2(-0.5f*(e1 + bq), beta[c*NTRAIN+t]);
    } else if (diag && tid < 256) {
        int n = tid - 128;
        float iN[12], tv[12];
        #pragma unroll
        for (int d = 0; d < 12; d++) iN[d] = (xi[d] - mu[d]) * sc_il[d];
        float qq = 0.f;
        #pragma unroll
        for (int d = 0; d < 12; d++) {
            float u = 0.f;
            #pragma unroll
            for (int cl = 0; cl < 12; cl++) u += Wg[d*12+cl]*iN[cl];
            tv[d] = u; qq += iN[d]*u;
        }
        float lb = __expf(-0.5f*qq) * beta[a*NTRAIN+n];
        float vals[13];
        vals[0] = lb;
        #pragma unroll
        for (int d = 0; d < 12; d++) vals[1+d] = tv[d]*sc_il[d]*lb;
        #pragma unroll
        for (int v = 0; v < 13; v++)
            #pragma unroll
            for (int off = 32; off >= 1; off >>= 1) vals[v] += __shfl_xor(vals[v], off, 64);
        if (lane == 0) {
            #pragma unroll
            for (int v = 0; v < 13; v++) redg[w-2][v] = vals[v];  // waves 2,3
        }
    }
    __syncthreads();

    // ---- stage 2b: sweep. lane owns j0=2l, 2l+1; wave w handles i = w + 8k. ----
    float4 bwv = ((const float4*)bw)[lane];   // {basej0, wc0, basej1, wc1}
    float basej0 = bwv.x, wc0 = bwv.y, basej1 = bwv.z, wc1 = bwv.w;
    float am0 = 0.f, am1 = 0.f, at0 = 0.f, at1 = 0.f;
    const float2* Kb = (const float2*)(invK + a*NTRAIN*NTRAIN);
    #pragma unroll 4
    for (int k = 0; k < 16; k++) {
        int i = w + 8*k;                         // wave-uniform -> LDS broadcast
        const float4* hp = (const float4*)&h[i][0];
        float4 h0 = hp[0], h1 = hp[1], h2 = hp[2];
        float2 h3 = *(const float2*)&h[i][12];   // {basei, wav}
        float sA0 = fmaf(h0.x,xa[0], fmaf(h0.y,xa[1], fmaf(h0.z,xa[2], h0.w*xa[3])));
        float sB0 = fmaf(h1.x,xa[4], fmaf(h1.y,xa[5], fmaf(h1.z,xa[6], h1.w*xa[7])));
        float sC0 = fmaf(h2.x,xa[8], fmaf(h2.y,xa[9], fmaf(h2.z,xa[10], h2.w*xa[11])));
        float sA1 = fmaf(h0.x,xb[0], fmaf(h0.y,xb[1], fmaf(h0.z,xb[2], h0.w*xb[3])));
        float sB1 = fmaf(h1.x,xb[4], fmaf(h1.y,xb[5], fmaf(h1.z,xb[6], h1.w*xb[7])));
        float sC1 = fmaf(h2.x,xb[8], fmaf(h2.y,xb[9], fmaf(h2.z,xb[10], h2.w*xb[11])));
        float e0  = __expf(sA0 + sB0 + sC0 + h3.x + basej0);
        float e1v = __expf(sA1 + sB1 + sC1 + h3.x + basej1);
        am0 = fmaf(h3.y, e0, am0);
        am1 = fmaf(h3.y, e1v, am1);
        if (diag) {
            float2 kv = Kb[i*64 + lane];          // Ka[i][2l], Ka[i][2l+1]
            at0 = fmaf(kv.x, e0, at0);
            at1 = fmaf(kv.y, e1v, at1);
        }
    }
    float accm = am0*wc0 + am1*wc1;
    float acct = at0 + at1;
    #pragma unroll
    for (int off = 32; off >= 1; off >>= 1) {
        accm += __shfl_xor(accm, off, 64);
        acct += __shfl_xor(acct, off, 64);
    }
    if (lane == 0) { red[w][0] = accm; red[w][1] = acct; }
    __syncthreads();
    if (tid == 0) {
        float m = 0.f, t = 0.f;
        #pragma unroll
        for (int v = 0; v < 8; v++) { m += red[v][0]; t += red[v][1]; }
        m *= s_cab; t *= s_cab;
        ws[WS_MN + b*64 + a*8 + c] = m;
        ws[WS_MN + b*64 + c*8 + a] = m;          // exact symmetry
        if (diag) ws[WS_TR + b*8 + a] = t;
    } else if (tid == 64 && diag) {
        float cn = s_cgp;
        ws[WS_PM + b*OBS + a] = cn*(redg[0][0]+redg[1][0]);
        #pragma unroll
        for (int d = 0; d < 12; d++)
            ws[WS_CC + (b*DIN+d)*OBS + a] = cn*(redg[0][1+d]+redg[1][1+d]);
    }
}

// ---------------------------------------------------------------------------
// Epilogue. 8 blocks x 64 threads. (Kernel boundary = device-wide release of
// k_fused's ws stores; no fences/atomics needed.)
// ---------------------------------------------------------------------------
__global__ void k_final(const float* __restrict__ m_x, const float* __restrict__ s_x,
                        const float* __restrict__ c_xu, const float* __restrict__ vars,
                        const float* __restrict__ noises, const float* __restrict__ ws,
                        float* __restrict__ out) {
    int b = blockIdx.x, t = threadIdx.x;
    __shared__ float pm[OBS];
    __shared__ float sxs[64];
    const float* cc = ws + WS_CC + b*DIN*OBS;
    const float* mn = ws + WS_MN + b*64;
    const float* tr = ws + WS_TR + b*OBS;
    sxs[t] = s_x[b*64 + t];
    if (t < OBS) {
        float p = ws[WS_PM + b*OBS + t];
        pm[t] = p;
        out[b*OBS + t] = m_x[b*OBS + t] + p;        // m_out
    }
    __syncthreads();
    int r = t >> 3, cl = t & 7;
    float P = mn[r*8 + cl];
    if (r == cl) P += vars[r] - tr[r] + noises[r];
    P -= pm[r]*pm[cl];
    float cxf = 0.f, cxfT = 0.f;
    #pragma unroll
    for (int d = 0; d < 8; d++) {
        cxf  += sxs[r*8+d]  * cc[d*8+cl];
        cxfT += sxs[cl*8+d] * cc[d*8+r];
    }
    #pragma unroll
    for (int d = 0; d < 4; d++) {
        float jr = 0.f, jc = 0.f;
        #pragma unroll
        for (int k = 0; k < 8; k++) {
            float cx = c_xu[(b*OBS+k)*ACT + d];
            jr += sxs[r*8+k]  * cx;
            jc += sxs[cl*8+k] * cx;
        }
        cxf  += jr * cc[(8+d)*8 + cl];
        cxfT += jc * cc[(8+d)*8 + r];
    }
    float S = sxs[r*8+cl] + P + cxf + cxfT;
    if (r == cl) S += 1e-8f;
    out[64 + b*64 + t] = S;                          // s_out
}

// ---------------------------------------------------------------------------
extern "C" void kernel_launch(void* const* d_in, const int* in_sizes, int n_in,
                              void* d_out, int out_size, void* d_ws, size_t ws_size,
                              hipStream_t stream) {
    const float* m_x    = (const float*)d_in[0];
    const float* s_x    = (const float*)d_in[1];
    const float* m_u    = (const float*)d_in[2];
    const float* s_u    = (const float*)d_in[3];
    const float* c_xu   = (const float*)d_in[4];
    const float* X      = (const float*)d_in[5];
    const float* ls     = (const float*)d_in[6];
    const float* vars   = (const float*)d_in[7];
    const float* noises = (const float*)d_in[8];
    const float* invK   = (const float*)d_in[9];
    const float* beta   = (const float*)d_in[10];
    float* out = (float*)d_out;
    float* ws  = (float*)d_ws;

    k_fused<<<NBLK, THREADS, 0, stream>>>(m_x, s_x, m_u, s_u, c_xu, X, ls, vars,
                                          beta, invK, ws);
    k_final<<<BATCH, 64, 0, stream>>>(m_x, s_x, c_xu, vars, noises, ws, out);
}

// Round 5
// 92.080 us; speedup vs baseline: 1.1577x; 1.0090x over previous
//
#include <hip/hip_runtime.h>
#include <math.h>

#define OBS 8
#define ACT 4
#define DIN 12
#define NTRAIN 128
#define BATCH 8
#define NBLK 288               // 64 diag(+gp) blocks + 224 off-diag pair blocks
#define THREADS 512
#define HSTRIDE 16             // floats per h row (64B; 2-way write alias = free)

// ws layout (floats)
#define WS_PM  0               // 64   pred_mean[b][e]
#define WS_CC  64              // 768  cross_cov[b][d][e]
#define WS_MN  832             // 512  main[b][a][c]
#define WS_TR  1344            // 64   trace[b][e]

// ---------------------------------------------------------------------------
// Main kernel: 288 blocks x 512 threads (8 waves), plain launch.
// Task map (XCD-aware): blk<64 -> diag task (b=blk>>3, a=c=blk&7) + gp task
// e=a. All 8 readers of invK[a] have blk%8==a -> same XCD -> L2 reuse of the
// 64KB matrix (first reader pulls from HBM, rest hit L2). blk 64..287 ->
// off-diag pairs (28 per batch, a<c).
// Diag blocks: dual shuffle-GJ in wave 0 (lanes 0..15 pair-M, 16..27 gp-B);
// gp point work on waves 2..3 concurrent with pair stage 2a on waves 0..1.
// Latency shaping: beta prefetched at entry; invK prefetched into kv[16]
// registers BEFORE the pre-sweep barrier (full static unroll - runtime
// indexing would spill to scratch); sweep fully unrolled.
// NOTE (round-2/3 lessons): do NOT add a min-waves __launch_bounds__ floor
// (spills xa/xb/xi, 2.5MB scratch traffic); do NOT replace k_final with an
// atomic last-block epilogue (memset dispatch + coherent-publish tail ~5us).
// ---------------------------------------------------------------------------
__global__ void __launch_bounds__(THREADS) k_fused(
    const float* __restrict__ m_x, const float* __restrict__ s_x,
    const float* __restrict__ m_u, const float* __restrict__ s_u,
    const float* __restrict__ c_xu, const float* __restrict__ X,
    const float* __restrict__ ls, const float* __restrict__ vars,
    const float* __restrict__ beta, const float* __restrict__ invK,
    float* __restrict__ ws)
{
    int blk = blockIdx.x, tid = threadIdx.x;
    int lane = tid & 63, w = tid >> 6;
    int b, a, c;
    bool diag = (blk < 64);
    if (diag) {
        b = blk >> 3; a = blk & 7; c = a;
    } else {
        int q = blk - 64; b = q / 28; int r = q % 28;
        a = 0;
        while (r >= 7 - a) { r -= 7 - a; a++; }
        c = a + 1 + r;
    }

    __shared__ float jvs[144];          // joint_var
    __shared__ float Wl[144];           // pair M-inverse
    __shared__ float Wg[144];           // gp B-inverse (diag blocks)
    __shared__ float mu[DIN];
    __shared__ float sc_wsum[DIN], sc_iA[DIN], sc_qc[DIN], sc_lam[DIN], sc_isum[DIN], sc_il[DIN];
    __shared__ float s_cab, s_cgp;
    __shared__ __align__(16) float h[NTRAIN][HSTRIDE];  // {h0..h11, basei, wav, pad2}
    __shared__ __align__(16) float2 bw[NTRAIN];         // {basej, wc}
    __shared__ float red[8][13];
    __shared__ float redg[2][16];       // gp wave partials (waves 2,3)

    // ---- entry prefetch: X rows + beta (all cold HBM misses issued in parallel,
    //      so later stages don't eat serial miss latency) ----
    int j0 = 2*lane;
    float xa[12], xb[12], xi[12];
    {
        const float4* xr = (const float4*)(X + j0*DIN);   // rows j0, j0+1 contiguous
        float4 t0 = xr[0], t1 = xr[1], t2 = xr[2], t3 = xr[3], t4 = xr[4], t5 = xr[5];
        xa[0]=t0.x; xa[1]=t0.y; xa[2]=t0.z; xa[3]=t0.w;
        xa[4]=t1.x; xa[5]=t1.y; xa[6]=t1.z; xa[7]=t1.w;
        xa[8]=t2.x; xa[9]=t2.y; xa[10]=t2.z; xa[11]=t2.w;
        xb[0]=t3.x; xb[1]=t3.y; xb[2]=t3.z; xb[3]=t3.w;
        xb[4]=t4.x; xb[5]=t4.y; xb[6]=t4.z; xb[7]=t4.w;
        xb[8]=t5.x; xb[9]=t5.y; xb[10]=t5.z; xb[11]=t5.w;
    }
    float ba = 0.f, bc = 0.f;
    if (tid < 256) {                   // rows for pair h (0..127) and gp points (128..255)
        int rowi = tid & 127;
        const float4* xr = (const float4*)(X + rowi*DIN);
        float4 t0 = xr[0], t1 = xr[1], t2 = xr[2];
        xi[0]=t0.x; xi[1]=t0.y; xi[2]=t0.z; xi[3]=t0.w;
        xi[4]=t1.x; xi[5]=t1.y; xi[6]=t1.z; xi[7]=t1.w;
        xi[8]=t2.x; xi[9]=t2.y; xi[10]=t2.z; xi[11]=t2.w;
        ba = beta[a*NTRAIN + rowi];    // pair i-side weight / gp weight
    }
    if (tid < NTRAIN) bc = beta[c*NTRAIN + tid];   // pair j-side weight

    // ---- stage 0: joint_var + per-dim scalars ----
    if (tid < 144) {
        int r = tid / 12, cl = tid % 12;
        float v;
        if (r < OBS && cl < OBS) {
            v = s_x[(b*OBS+r)*OBS + cl];
        } else if (r < OBS) {
            v = 0.f;
            #pragma unroll
            for (int k = 0; k < OBS; k++)
                v += s_x[(b*OBS+r)*OBS+k] * c_xu[(b*OBS+k)*ACT + (cl-OBS)];
        } else if (cl < OBS) {
            v = 0.f;
            #pragma unroll
            for (int k = 0; k < OBS; k++)
                v += s_x[(b*OBS+cl)*OBS+k] * c_xu[(b*OBS+k)*ACT + (r-OBS)];
        } else {
            v = s_u[(b*ACT+r-OBS)*ACT + (cl-OBS)];
        }
        jvs[tid] = v;
    } else if (tid >= 160 && tid < 172) {
        int d = tid - 160;
        mu[d] = (d < OBS) ? m_x[b*OBS+d] : m_u[b*ACT+d-OBS];
    } else if (tid >= 192 && tid < 204) {
        int d = tid - 192;
        float la = ls[a*DIN+d]; la *= la;
        float lc = ls[c*DIN+d]; lc *= lc;
        float ia = 1.f/la, ic = 1.f/lc;
        float is = ia + ic;
        float L  = 1.f/is;
        sc_wsum[d] = 1.f/(la+lc);
        sc_iA[d] = L*ia;       // r_i = iA*x_i - mu
        sc_qc[d] = L*ic;       // q_j = qc*x_j
        sc_lam[d] = L;
        sc_isum[d] = is;
    } else if (tid >= 224 && tid < 236) {
        int d = tid - 224;
        sc_il[d] = 1.f / ls[a*DIN+d];   // gp inv lengthscale (e=a; only read when diag)
    }
    __syncthreads();

    // ---- stage 1: dual 12-lane shuffle Gauss-Jordan in wave 0 ----
    // lanes 0..15 (grp 0): pair M = jv + diag(Lam)   [12..15 are padding lanes]
    // lanes 16..27 (grp 1): gp  B = il*jv*il + I
    if (tid < 64 && lane < 28) {
        int grp = lane >> 4;
        int base = grp << 4;
        int r = lane - base;
        int rr = (r < 12) ? r : 0;      // clamp padding lanes' row index
        float row[12];
        if (grp == 0) {
            #pragma unroll
            for (int j = 0; j < 12; j++) row[j] = jvs[rr*12+j];
            row[rr] += sc_lam[rr];
        } else {
            float ir = sc_il[r];
            #pragma unroll
            for (int j = 0; j < 12; j++) row[j] = ir * sc_il[j] * jvs[r*12+j];
            row[r] += 1.f;
        }
        float det = 1.f;
        #pragma unroll
        for (int k = 0; k < 12; k++) {
            float p = __shfl(row[k], base + k);
            float ip = 1.f / p;
            det *= p;
            float prow[12];
            #pragma unroll
            for (int j = 0; j < 12; j++) prow[j] = __shfl(row[j], base + k) * ip;
            if (r == k) {
                #pragma unroll
                for (int j = 0; j < 12; j++) row[j] = prow[j];
                row[k] = ip;
            } else {
                float f = row[k];
                #pragma unroll
                for (int j = 0; j < 12; j++) if (j != k) row[j] -= f * prow[j];
                row[k] = -f * ip;
            }
        }
        if (r < 12) {
            float* W = grp ? Wg : Wl;
            #pragma unroll
            for (int j = 0; j < 12; j++) W[r*12+j] = row[j];
        }
        if (lane == 0) {
            float s = det;                          // det(R)=det(M)*prod(isum)
            #pragma unroll
            for (int d = 0; d < 12; d++) s *= sc_isum[d];
            s_cab = vars[a]*vars[c] / sqrtf(s);
        }
        if (lane == 16) s_cgp = vars[a] / sqrtf(det);
    }
    __syncthreads();

    // ---- stage 2a: pair h/bw on threads 0..127; gp points on threads 128..255 ----
    if (tid < NTRAIN) {
        int t = tid;
        float r[12], q[12]; float e1 = 0.f;
        #pragma unroll
        for (int d = 0; d < 12; d++) {
            r[d] = sc_iA[d]*xi[d] - mu[d];
            q[d] = sc_qc[d]*xi[d];
            e1 += sc_wsum[d]*xi[d]*xi[d];      // shared by i- and j-side
        }
        float hrow[16];
        float alpha = 0.f, bq = 0.f;
        #pragma unroll
        for (int d = 0; d < 12; d++) {
            float u = 0.f, uq = 0.f;
            #pragma unroll
            for (int cl = 0; cl < 12; cl++) {
                float wv = Wl[d*12+cl];
                u  += wv*r[cl];
                uq += wv*q[cl];
            }
            alpha += r[d]*u;
            bq    += q[d]*uq;
            hrow[d] = sc_wsum[d]*xi[d] - u*sc_qc[d];   // folded cross term
        }
        hrow[12] = -0.5f*(e1 + alpha);                 // basei
        hrow[13] = ba;                                 // wav (prefetched)
        hrow[14] = 0.f; hrow[15] = 0.f;
        float4* hp = (float4*)&h[t][0];
        hp[0] = make_float4(hrow[0],hrow[1],hrow[2],hrow[3]);
        hp[1] = make_float4(hrow[4],hrow[5],hrow[6],hrow[7]);
        hp[2] = make_float4(hrow[8],hrow[9],hrow[10],hrow[11]);
        hp[3] = make_float4(hrow[12],hrow[13],hrow[14],hrow[15]);
        bw[t] = make_float2(-0.5f*(e1 + bq), bc);
    } else if (diag && tid < 256) {
        int n = tid - 128;
        float iN[12], tv[12];
        #pragma unroll
        for (int d = 0; d < 12; d++) iN[d] = (xi[d] - mu[d]) * sc_il[d];
        float qq = 0.f;
        #pragma unroll
        for (int d = 0; d < 12; d++) {
            float u = 0.f;
            #pragma unroll
            for (int cl = 0; cl < 12; cl++) u += Wg[d*12+cl]*iN[cl];
            tv[d] = u; qq += iN[d]*u;
        }
        float lb = __expf(-0.5f*qq) * ba;   // ba = beta[a][n] (prefetched)
        float vals[13];
        vals[0] = lb;
        #pragma unroll
        for (int d = 0; d < 12; d++) vals[1+d] = tv[d]*sc_il[d]*lb;
        #pragma unroll
        for (int v = 0; v < 13; v++)
            #pragma unroll
            for (int off = 32; off >= 1; off >>= 1) vals[v] += __shfl_xor(vals[v], off, 64);
        if (lane == 0) {
            #pragma unroll
            for (int v = 0; v < 13; v++) redg[w-2][v] = vals[v];  // waves 2,3
        }
    }

    // ---- invK register prefetch (diag only): issue BEFORE the barrier so the
    //      cold HBM latency hides under barrier + sweep prologue. kv[] must be
    //      statically indexed (full unroll) or it spills to scratch. ----
    const float2* Kb = (const float2*)(invK + a*NTRAIN*NTRAIN);
    float2 kv[16];
    if (diag) {
        #pragma unroll
        for (int k = 0; k < 16; k++) kv[k] = Kb[(w + 8*k)*64 + lane];
    }
    __syncthreads();

    // ---- stage 2b: sweep. lane owns j0=2l, 2l+1; wave w handles i = w + 8k. ----
    float4 bwv = ((const float4*)bw)[lane];   // {basej0, wc0, basej1, wc1}
    float basej0 = bwv.x, wc0 = bwv.y, basej1 = bwv.z, wc1 = bwv.w;
    float am0 = 0.f, am1 = 0.f, at0 = 0.f, at1 = 0.f;
    #pragma unroll
    for (int k = 0; k < 16; k++) {
        int i = w + 8*k;                         // wave-uniform -> LDS broadcast
        const float4* hp = (const float4*)&h[i][0];
        float4 h0 = hp[0], h1 = hp[1], h2 = hp[2];
        float2 h3 = *(const float2*)&h[i][12];   // {basei, wav}
        float sA0 = fmaf(h0.x,xa[0], fmaf(h0.y,xa[1], fmaf(h0.z,xa[2], h0.w*xa[3])));
        float sB0 = fmaf(h1.x,xa[4], fmaf(h1.y,xa[5], fmaf(h1.z,xa[6], h1.w*xa[7])));
        float sC0 = fmaf(h2.x,xa[8], fmaf(h2.y,xa[9], fmaf(h2.z,xa[10], h2.w*xa[11])));
        float sA1 = fmaf(h0.x,xb[0], fmaf(h0.y,xb[1], fmaf(h0.z,xb[2], h0.w*xb[3])));
        float sB1 = fmaf(h1.x,xb[4], fmaf(h1.y,xb[5], fmaf(h1.z,xb[6], h1.w*xb[7])));
        float sC1 = fmaf(h2.x,xb[8], fmaf(h2.y,xb[9], fmaf(h2.z,xb[10], h2.w*xb[11])));
        float e0  = __expf(sA0 + sB0 + sC0 + h3.x + basej0);
        float e1v = __expf(sA1 + sB1 + sC1 + h3.x + basej1);
        am0 = fmaf(h3.y, e0, am0);
        am1 = fmaf(h3.y, e1v, am1);
        if (diag) {
            at0 = fmaf(kv[k].x, e0, at0);
            at1 = fmaf(kv[k].y, e1v, at1);
        }
    }
    float accm = am0*wc0 + am1*wc1;
    float acct = at0 + at1;
    #pragma unroll
    for (int off = 32; off >= 1; off >>= 1) {
        accm += __shfl_xor(accm, off, 64);
        acct += __shfl_xor(acct, off, 64);
    }
    if (lane == 0) { red[w][0] = accm; red[w][1] = acct; }
    __syncthreads();
    if (tid == 0) {
        float m = 0.f, t = 0.f;
        #pragma unroll
        for (int v = 0; v < 8; v++) { m += red[v][0]; t += red[v][1]; }
        m *= s_cab; t *= s_cab;
        ws[WS_MN + b*64 + a*8 + c] = m;
        ws[WS_MN + b*64 + c*8 + a] = m;          // exact symmetry
        if (diag) ws[WS_TR + b*8 + a] = t;
    } else if (tid == 64 && diag) {
        float cn = s_cgp;
        ws[WS_PM + b*OBS + a] = cn*(redg[0][0]+redg[1][0]);
        #pragma unroll
        for (int d = 0; d < 12; d++)
            ws[WS_CC + (b*DIN+d)*OBS + a] = cn*(redg[0][1+d]+redg[1][1+d]);
    }
}

// ---------------------------------------------------------------------------
// Epilogue. 8 blocks x 64 threads. (Kernel boundary = device-wide release of
// k_fused's ws stores; no fences/atomics needed.)
// ---------------------------------------------------------------------------
__global__ void k_final(const float* __restrict__ m_x, const float* __restrict__ s_x,
                        const float* __restrict__ c_xu, const float* __restrict__ vars,
                        const float* __restrict__ noises, const float* __restrict__ ws,
                        float* __restrict__ out) {
    int b = blockIdx.x, t = threadIdx.x;
    __shared__ float pm[OBS];
    __shared__ float sxs[64];
    const float* cc = ws + WS_CC + b*DIN*OBS;
    const float* mn = ws + WS_MN + b*64;
    const float* tr = ws + WS_TR + b*OBS;
    sxs[t] = s_x[b*64 + t];
    if (t < OBS) {
        float p = ws[WS_PM + b*OBS + t];
        pm[t] = p;
        out[b*OBS + t] = m_x[b*OBS + t] + p;        // m_out
    }
    __syncthreads();
    int r = t >> 3, cl = t & 7;
    float P = mn[r*8 + cl];
    if (r == cl) P += vars[r] - tr[r] + noises[r];
    P -= pm[r]*pm[cl];
    float cxf = 0.f, cxfT = 0.f;
    #pragma unroll
    for (int d = 0; d < 8; d++) {
        cxf  += sxs[r*8+d]  * cc[d*8+cl];
        cxfT += sxs[cl*8+d] * cc[d*8+r];
    }
    #pragma unroll
    for (int d = 0; d < 4; d++) {
        float jr = 0.f, jc = 0.f;
        #pragma unroll
        for (int k = 0; k < 8; k++) {
            float cx = c_xu[(b*OBS+k)*ACT + d];
            jr += sxs[r*8+k]  * cx;
            jc += sxs[cl*8+k] * cx;
        }
        cxf  += jr * cc[(8+d)*8 + cl];
        cxfT += jc * cc[(8+d)*8 + r];
    }
    float S = sxs[r*8+cl] + P + cxf + cxfT;
    if (r == cl) S += 1e-8f;
    out[64 + b*64 + t] = S;                          // s_out
}

// ---------------------------------------------------------------------------
extern "C" void kernel_launch(void* const* d_in, const int* in_sizes, int n_in,
                              void* d_out, int out_size, void* d_ws, size_t ws_size,
                              hipStream_t stream) {
    const float* m_x    = (const float*)d_in[0];
    const float* s_x    = (const float*)d_in[1];
    const float* m_u    = (const float*)d_in[2];
    const float* s_u    = (const float*)d_in[3];
    const float* c_xu   = (const float*)d_in[4];
    const float* X      = (const float*)d_in[5];
    const float* ls     = (const float*)d_in[6];
    const float* vars   = (const float*)d_in[7];
    const float* noises = (const float*)d_in[8];
    const float* invK   = (const float*)d_in[9];
    const float* beta   = (const float*)d_in[10];
    float* out = (float*)d_out;
    float* ws  = (float*)d_ws;

    k_fused<<<NBLK, THREADS, 0, stream>>>(m_x, s_x, m_u, s_u, c_xu, X, ls, vars,
                                          beta, invK, ws);
    k_final<<<BATCH, 64, 0, stream>>>(m_x, s_x, c_xu, vars, noises, ws, out);
}